// Round 2
// baseline (1877.350 us; speedup 1.0000x reference)
//
#include <hip/hip_runtime.h>
#include <hip/hip_bf16.h>
#include <math.h>

#define B_ 8
#define L_ 2048
#define ENC_IN_ 32
#define DM_ 512
#define DI_ 1024
#define DS_ 16
#define NM_ 4

__device__ __forceinline__ float sigmoid_f(float x) {
    return 1.f / (1.f + __expf(-x));
}
__device__ __forceinline__ float softplus_f(float v) {
    return fmaxf(v, 0.f) + log1pf(__expf(-fabsf(v)));
}

// ---------------- 1. DataEmbedding: circular conv(k=3) + timeF linear + pos ----------------
// grid: CB * 128 blocks (16 l's per block), 256 threads (each 2 d's)
__global__ __launch_bounds__(256)
void embed_kernel(const float* __restrict__ x_enc, const float* __restrict__ x_mark,
                  const float* __restrict__ pos_emb, const float* __restrict__ cw,
                  const float* __restrict__ tw, float* __restrict__ x) {
    __shared__ float sx[18 * 32];
    __shared__ float sm[16 * 4];
    const int blk = blockIdx.x;
    const int b = blk >> 7, lc = blk & 127;
    const int l0 = lc << 4;
    const int tid = threadIdx.x;
    for (int i = tid; i < 18 * 32; i += 256) {
        int row = i >> 5, c = i & 31;
        int lt = (l0 + row - 1 + L_) & (L_ - 1);  // circular
        sx[i] = x_enc[((size_t)b * L_ + lt) * ENC_IN_ + c];
    }
    for (int i = tid; i < 64; i += 256) {
        int row = i >> 2;
        sm[i] = x_mark[((size_t)b * L_ + l0 + row) * NM_ + (i & 3)];
    }
    __syncthreads();
    #pragma unroll
    for (int half = 0; half < 2; ++half) {
        const int d = tid + (half << 8);
        float acc[16];
        #pragma unroll
        for (int l = 0; l < 16; ++l) acc[l] = 0.f;
        for (int i = 0; i < 96; ++i) {
            const int k = i >> 5, c = i & 31;
            const float w = cw[(size_t)i * DM_ + d];  // conv_tok_w[k][c][d]
            #pragma unroll
            for (int l = 0; l < 16; ++l)
                acc[l] += sx[(l + k) * 32 + c] * w;
        }
        const float4 tww = *(const float4*)&tw[d * 4];
        #pragma unroll
        for (int l = 0; l < 16; ++l) {
            float s = acc[l] + pos_emb[(size_t)(l0 + l) * DM_ + d];
            s += sm[l * 4 + 0] * tww.x + sm[l * 4 + 1] * tww.y +
                 sm[l * 4 + 2] * tww.z + sm[l * 4 + 3] * tww.w;
            x[((size_t)b * L_ + l0 + l) * DM_ + d] = s;
        }
    }
}

// ---------------- fp32 NT GEMM: C[m,n] = sum_k A[m,k]*B[n,k]  (64x64x16 tile) ----------------
// EPI 0: none.  EPI 1: softplus(acc + bias[n])
template <int EPI>
__global__ __launch_bounds__(256)
void gemm_nt(const float* __restrict__ A, int lda,
             const float* __restrict__ Bw, int ldb,
             float* __restrict__ C, int ldc,
             const float* __restrict__ bias, int K) {
    __shared__ float as[16][68];
    __shared__ float bs[16][68];
    const int tid = threadIdx.x;
    const int tx = tid & 15, ty = tid >> 4;
    const int m0 = blockIdx.y << 6, n0 = blockIdx.x << 6;
    const int lrow = tid >> 2;
    const int lk4 = (tid & 3) << 2;
    float acc[4][4];
    #pragma unroll
    for (int i = 0; i < 4; ++i)
        #pragma unroll
        for (int j = 0; j < 4; ++j) acc[i][j] = 0.f;
    const float* Ap = A + (size_t)(m0 + lrow) * lda + lk4;
    const float* Bp = Bw + (size_t)(n0 + lrow) * ldb + lk4;
    for (int k0 = 0; k0 < K; k0 += 16) {
        const float4 av = *(const float4*)(Ap + k0);
        const float4 bv = *(const float4*)(Bp + k0);
        __syncthreads();
        as[lk4 + 0][lrow] = av.x; as[lk4 + 1][lrow] = av.y;
        as[lk4 + 2][lrow] = av.z; as[lk4 + 3][lrow] = av.w;
        bs[lk4 + 0][lrow] = bv.x; bs[lk4 + 1][lrow] = bv.y;
        bs[lk4 + 2][lrow] = bv.z; bs[lk4 + 3][lrow] = bv.w;
        __syncthreads();
        #pragma unroll
        for (int kk = 0; kk < 16; ++kk) {
            const float4 a4 = *(const float4*)&as[kk][ty << 2];
            const float4 b4 = *(const float4*)&bs[kk][tx << 2];
            acc[0][0] += a4.x * b4.x; acc[0][1] += a4.x * b4.y;
            acc[0][2] += a4.x * b4.z; acc[0][3] += a4.x * b4.w;
            acc[1][0] += a4.y * b4.x; acc[1][1] += a4.y * b4.y;
            acc[1][2] += a4.y * b4.z; acc[1][3] += a4.y * b4.w;
            acc[2][0] += a4.z * b4.x; acc[2][1] += a4.z * b4.y;
            acc[2][2] += a4.z * b4.z; acc[2][3] += a4.z * b4.w;
            acc[3][0] += a4.w * b4.x; acc[3][1] += a4.w * b4.y;
            acc[3][2] += a4.w * b4.z; acc[3][3] += a4.w * b4.w;
        }
    }
    #pragma unroll
    for (int i = 0; i < 4; ++i) {
        const int row = m0 + (ty << 2) + i;
        const int col = n0 + (tx << 2);
        float4 o;
        o.x = acc[i][0]; o.y = acc[i][1]; o.z = acc[i][2]; o.w = acc[i][3];
        if (EPI == 1) {
            o.x = softplus_f(o.x + bias[col + 0]);
            o.y = softplus_f(o.y + bias[col + 1]);
            o.z = softplus_f(o.z + bias[col + 2]);
            o.w = softplus_f(o.w + bias[col + 3]);
        }
        *(float4*)&C[(size_t)row * ldc + col] = o;
    }
}

// ---------------- 3. causal depthwise conv1d (k=4) + bias + silu ----------------
// xm stride = DI_ (separate buffer now)
__global__ __launch_bounds__(256)
void dwconv_silu_kernel(const float* __restrict__ xm, const float* __restrict__ cw,
                        const float* __restrict__ cb, float* __restrict__ u) {
    const int idx = blockIdx.x * 256 + threadIdx.x;  // one per 4 channels
    const int m = idx >> 8;
    const int q = (idx & 255) << 2;
    const int t = m & (L_ - 1);
    float4 acc = *(const float4*)&cb[q];
    #pragma unroll
    for (int k = 0; k < 4; ++k) {
        const int tt = t - 3 + k;
        if (tt >= 0) {
            const float4 xv = *(const float4*)&xm[(size_t)(m - 3 + k) * DI_ + q];
            const float4 wv = *(const float4*)&cw[k * DI_ + q];
            acc.x += xv.x * wv.x; acc.y += xv.y * wv.y;
            acc.z += xv.z * wv.z; acc.w += xv.w * wv.w;
        }
    }
    acc.x *= sigmoid_f(acc.x); acc.y *= sigmoid_f(acc.y);
    acc.z *= sigmoid_f(acc.z); acc.w *= sigmoid_f(acc.w);
    *(float4*)&u[(size_t)m * DI_ + q] = acc;
}

// ---------------- 6. selective scan, fused with +u*D and *silu(z) gating ----------------
// all activation strides = DI_; y written IN PLACE over z
#define SCAN_LOAD(S, t_) { \
    const size_t mm_ = mbase + (size_t)(t_); \
    de##S = dptr[mm_ * DI_ + d]; \
    uu##S = uptr[mm_ * DI_ + d]; \
    zz##S = zyptr[mm_ * DI_ + d]; \
    const float4* bcp_ = (const float4*)&dbc[mm_ * 64 + 32]; \
    vb0##S = bcp_[0]; vb1##S = bcp_[1]; vb2##S = bcp_[2]; vb3##S = bcp_[3]; \
    vc0##S = bcp_[4]; vc1##S = bcp_[5]; vc2##S = bcp_[6]; vc3##S = bcp_[7]; \
}

#define SSTEP(n_, bb_, cc_) { const float dA_ = __expf(de_ * A[n_]); \
    h[n_] = dA_ * h[n_] + du_ * (bb_); y_ += h[n_] * (cc_); }
#define SGRP(b_, vb_, vc_) SSTEP(b_ + 0, vb_.x, vc_.x) SSTEP(b_ + 1, vb_.y, vc_.y) \
    SSTEP(b_ + 2, vb_.z, vc_.z) SSTEP(b_ + 3, vb_.w, vc_.w)

#define SCAN_COMP(S, t_) { \
    const float de_ = de##S; const float du_ = de##S * uu##S; float y_ = 0.f; \
    SGRP(0, vb0##S, vc0##S) SGRP(4, vb1##S, vc1##S) \
    SGRP(8, vb2##S, vc2##S) SGRP(12, vb3##S, vc3##S) \
    const float zv_ = zz##S; \
    const float yo_ = (y_ + uu##S * Dv) * (zv_ * sigmoid_f(zv_)); \
    zyptr[(mbase + (size_t)(t_)) * DI_ + d] = yo_; \
}

__global__ __launch_bounds__(64)
void scan_kernel(const float* __restrict__ dptr, const float* __restrict__ uptr,
                 const float* __restrict__ dbc, float* __restrict__ zyptr,
                 const float* __restrict__ A_log, const float* __restrict__ Dp) {
    const int lane = threadIdx.x;
    const int blk = blockIdx.x;          // CB*16 blocks: 16 per batch
    const int b = blk >> 4;
    const int d = ((blk & 15) << 6) + lane;
    float A[16], h[16];
    #pragma unroll
    for (int n = 0; n < 16; ++n) {
        A[n] = -expf(A_log[(size_t)d * DS_ + n]);
        h[n] = 0.f;
    }
    const float Dv = Dp[d];
    const size_t mbase = (size_t)b * L_;
    float dea, uua, zza, deb, uub, zzb;
    float4 vb0a, vb1a, vb2a, vb3a, vc0a, vc1a, vc2a, vc3a;
    float4 vb0b, vb1b, vb2b, vb3b, vc0b, vc1b, vc2b, vc3b;
    SCAN_LOAD(a, 0)
    for (int t = 0; t < L_; t += 2) {
        SCAN_LOAD(b, t + 1)
        SCAN_COMP(a, t)
        if (t + 2 < L_) { SCAN_LOAD(a, t + 2) }
        SCAN_COMP(b, t + 1)
    }
}

// ---------------- 8. final projection (N=1) ----------------
__global__ __launch_bounds__(64)
void finalproj_kernel(const float* __restrict__ xo, const float* __restrict__ pw,
                      const float* __restrict__ pb, float* __restrict__ out) {
    const int m = blockIdx.x;
    const int lane = threadIdx.x;
    const float4 a0 = *(const float4*)&xo[(size_t)m * DM_ + lane * 4];
    const float4 a1 = *(const float4*)&xo[(size_t)m * DM_ + 256 + lane * 4];
    const float4 w0 = *(const float4*)&pw[lane * 4];
    const float4 w1 = *(const float4*)&pw[256 + lane * 4];
    float s = a0.x * w0.x + a0.y * w0.y + a0.z * w0.z + a0.w * w0.w +
              a1.x * w1.x + a1.y * w1.y + a1.z * w1.z + a1.w * w1.w;
    #pragma unroll
    for (int off = 32; off; off >>= 1) s += __shfl_down(s, off);
    if (lane == 0) out[m] = s + pb[0];
}

extern "C" void kernel_launch(void* const* d_in, const int* in_sizes, int n_in,
                              void* d_out, int out_size, void* d_ws, size_t ws_size,
                              hipStream_t stream) {
    const float* x_enc     = (const float*)d_in[0];
    const float* x_mark    = (const float*)d_in[1];
    const float* pos_emb   = (const float*)d_in[4];
    const float* conv_tok_w= (const float*)d_in[5];
    const float* temp_w    = (const float*)d_in[6];
    const float* in_proj_w = (const float*)d_in[7];
    const float* conv1d_w  = (const float*)d_in[8];
    const float* conv1d_b  = (const float*)d_in[9];
    const float* x_proj_w  = (const float*)d_in[10];
    const float* dt_proj_w = (const float*)d_in[11];
    const float* dt_proj_b = (const float*)d_in[12];
    const float* A_log     = (const float*)d_in[13];
    const float* D_param   = (const float*)d_in[14];
    const float* out_proj_w= (const float*)d_in[15];
    const float* proj_w    = (const float*)d_in[16];
    const float* proj_b    = (const float*)d_in[17];

    // per-batch region sizes (floats)
    const size_t R4b = (size_t)L_ * DM_;   // x / dbc   (1M)
    const size_t R1b = (size_t)L_ * DI_;   // xm / delta (2M)
    // R2b = z/y, R3b = u/x_out, both = R1b
    const size_t perBatchFloats = R4b + 3 * R1b;  // 7M floats = 28MB

    // pick batch-chunk size CB that fits ws
    int CB = 8;
    while (CB > 1 && (size_t)CB * perBatchFloats * sizeof(float) > ws_size) CB >>= 1;

    for (int c0 = 0; c0 < B_; c0 += CB) {
        const size_t Mc = (size_t)CB * L_;
        float* R4 = (float*)d_ws;              // x, later dbc
        float* R1 = R4 + CB * R4b;             // xm, later delta
        float* R2 = R1 + CB * R1b;             // z, y (in place)
        float* R3 = R2 + CB * R1b;             // u, later x_out

        const float* xe  = x_enc  + (size_t)c0 * L_ * ENC_IN_;
        const float* xme = x_mark + (size_t)c0 * L_ * NM_;
        float* outc = (float*)d_out + (size_t)c0 * L_;

        // 1. embedding -> x (R4)
        embed_kernel<<<dim3(CB * 128), 256, 0, stream>>>(xe, xme, pos_emb,
                                                         conv_tok_w, temp_w, R4);
        // 2a. in_proj (xm half): [Mc,512] x [1024,512]^T -> xm (R1)
        gemm_nt<0><<<dim3(DI_ / 64, Mc / 64), 256, 0, stream>>>(
            R4, DM_, in_proj_w, DM_, R1, DI_, nullptr, DM_);
        // 2b. in_proj (z half) -> z (R2)
        gemm_nt<0><<<dim3(DI_ / 64, Mc / 64), 256, 0, stream>>>(
            R4, DM_, in_proj_w + (size_t)DI_ * DM_, DM_, R2, DI_, nullptr, DM_);
        // 3. depthwise causal conv + silu -> u (R3)
        dwconv_silu_kernel<<<dim3(Mc), 256, 0, stream>>>(R1, conv1d_w, conv1d_b, R3);
        // 4. x_proj: [Mc,1024] x [64,1024]^T -> dbc (R4, x dead)
        gemm_nt<0><<<dim3(1, Mc / 64), 256, 0, stream>>>(
            R3, DI_, x_proj_w, DI_, R4, 64, nullptr, DI_);
        // 5. dt_proj + softplus: [Mc,32](lda=64) x [1024,32]^T -> delta (R1, xm dead)
        gemm_nt<1><<<dim3(DI_ / 64, Mc / 64), 256, 0, stream>>>(
            R4, 64, dt_proj_w, 32, R1, DI_, dt_proj_b, 32);
        // 6. selective scan + gating: y overwrites z in place (R2)
        scan_kernel<<<dim3(CB * 16), 64, 0, stream>>>(R1, R3, R4, R2,
                                                      A_log, D_param);
        // 7. out_proj: y [Mc,1024] x [512,1024]^T -> x_out (R3, u dead)
        gemm_nt<0><<<dim3(DM_ / 64, Mc / 64), 256, 0, stream>>>(
            R2, DI_, out_proj_w, DI_, R3, DM_, nullptr, DI_);
        // 8. final projection -> out [Mc,1]
        finalproj_kernel<<<dim3(Mc), 64, 0, stream>>>(R3, proj_w, proj_b, outc);
    }
}

// Round 3
// 1167.975 us; speedup vs baseline: 1.6074x; 1.6074x over previous
//
#include <hip/hip_runtime.h>
#include <hip/hip_bf16.h>
#include <math.h>

#define B_ 8
#define L_ 2048
#define ENC_IN_ 32
#define DM_ 512
#define DI_ 1024
#define DS_ 16
#define NM_ 4
#define NC_ 16    // chunks per sequence
#define TC_ 128   // chunk length (NC_*TC_ == L_)

__device__ __forceinline__ float sigmoid_f(float x) {
    return 1.f / (1.f + __expf(-x));
}
__device__ __forceinline__ float softplus_f(float v) {
    return fmaxf(v, 0.f) + log1pf(__expf(-fabsf(v)));
}

// ---------------- 1. DataEmbedding: circular conv(k=3) + timeF linear + pos ----------------
__global__ __launch_bounds__(256)
void embed_kernel(const float* __restrict__ x_enc, const float* __restrict__ x_mark,
                  const float* __restrict__ pos_emb, const float* __restrict__ cw,
                  const float* __restrict__ tw, float* __restrict__ x) {
    __shared__ float sx[18 * 32];
    __shared__ float sm[16 * 4];
    const int blk = blockIdx.x;
    const int b = blk >> 7, lc = blk & 127;
    const int l0 = lc << 4;
    const int tid = threadIdx.x;
    for (int i = tid; i < 18 * 32; i += 256) {
        int row = i >> 5, c = i & 31;
        int lt = (l0 + row - 1 + L_) & (L_ - 1);  // circular
        sx[i] = x_enc[((size_t)b * L_ + lt) * ENC_IN_ + c];
    }
    for (int i = tid; i < 64; i += 256) {
        int row = i >> 2;
        sm[i] = x_mark[((size_t)b * L_ + l0 + row) * NM_ + (i & 3)];
    }
    __syncthreads();
    #pragma unroll
    for (int half = 0; half < 2; ++half) {
        const int d = tid + (half << 8);
        float acc[16];
        #pragma unroll
        for (int l = 0; l < 16; ++l) acc[l] = 0.f;
        for (int i = 0; i < 96; ++i) {
            const int k = i >> 5, c = i & 31;
            const float w = cw[(size_t)i * DM_ + d];  // conv_tok_w[k][c][d]
            #pragma unroll
            for (int l = 0; l < 16; ++l)
                acc[l] += sx[(l + k) * 32 + c] * w;
        }
        const float4 tww = *(const float4*)&tw[d * 4];
        #pragma unroll
        for (int l = 0; l < 16; ++l) {
            float s = acc[l] + pos_emb[(size_t)(l0 + l) * DM_ + d];
            s += sm[l * 4 + 0] * tww.x + sm[l * 4 + 1] * tww.y +
                 sm[l * 4 + 2] * tww.z + sm[l * 4 + 3] * tww.w;
            x[((size_t)b * L_ + l0 + l) * DM_ + d] = s;
        }
    }
}

// ---------------- fp32 NT GEMM: C[m,n] = sum_k A[m,k]*B[n,k]  (64x64x16 tile) ----------------
template <int EPI>
__global__ __launch_bounds__(256)
void gemm_nt(const float* __restrict__ A, int lda,
             const float* __restrict__ Bw, int ldb,
             float* __restrict__ C, int ldc,
             const float* __restrict__ bias, int K) {
    __shared__ float as[16][68];
    __shared__ float bs[16][68];
    const int tid = threadIdx.x;
    const int tx = tid & 15, ty = tid >> 4;
    const int m0 = blockIdx.y << 6, n0 = blockIdx.x << 6;
    const int lrow = tid >> 2;
    const int lk4 = (tid & 3) << 2;
    float acc[4][4];
    #pragma unroll
    for (int i = 0; i < 4; ++i)
        #pragma unroll
        for (int j = 0; j < 4; ++j) acc[i][j] = 0.f;
    const float* Ap = A + (size_t)(m0 + lrow) * lda + lk4;
    const float* Bp = Bw + (size_t)(n0 + lrow) * ldb + lk4;
    for (int k0 = 0; k0 < K; k0 += 16) {
        const float4 av = *(const float4*)(Ap + k0);
        const float4 bv = *(const float4*)(Bp + k0);
        __syncthreads();
        as[lk4 + 0][lrow] = av.x; as[lk4 + 1][lrow] = av.y;
        as[lk4 + 2][lrow] = av.z; as[lk4 + 3][lrow] = av.w;
        bs[lk4 + 0][lrow] = bv.x; bs[lk4 + 1][lrow] = bv.y;
        bs[lk4 + 2][lrow] = bv.z; bs[lk4 + 3][lrow] = bv.w;
        __syncthreads();
        #pragma unroll
        for (int kk = 0; kk < 16; ++kk) {
            const float4 a4 = *(const float4*)&as[kk][ty << 2];
            const float4 b4 = *(const float4*)&bs[kk][tx << 2];
            acc[0][0] += a4.x * b4.x; acc[0][1] += a4.x * b4.y;
            acc[0][2] += a4.x * b4.z; acc[0][3] += a4.x * b4.w;
            acc[1][0] += a4.y * b4.x; acc[1][1] += a4.y * b4.y;
            acc[1][2] += a4.y * b4.z; acc[1][3] += a4.y * b4.w;
            acc[2][0] += a4.z * b4.x; acc[2][1] += a4.z * b4.y;
            acc[2][2] += a4.z * b4.z; acc[2][3] += a4.z * b4.w;
            acc[3][0] += a4.w * b4.x; acc[3][1] += a4.w * b4.y;
            acc[3][2] += a4.w * b4.z; acc[3][3] += a4.w * b4.w;
        }
    }
    #pragma unroll
    for (int i = 0; i < 4; ++i) {
        const int row = m0 + (ty << 2) + i;
        const int col = n0 + (tx << 2);
        float4 o;
        o.x = acc[i][0]; o.y = acc[i][1]; o.z = acc[i][2]; o.w = acc[i][3];
        if (EPI == 1) {
            o.x = softplus_f(o.x + bias[col + 0]);
            o.y = softplus_f(o.y + bias[col + 1]);
            o.z = softplus_f(o.z + bias[col + 2]);
            o.w = softplus_f(o.w + bias[col + 3]);
        }
        *(float4*)&C[(size_t)row * ldc + col] = o;
    }
}

// ---------------- 3. causal depthwise conv1d (k=4) + bias + silu ----------------
__global__ __launch_bounds__(256)
void dwconv_silu_kernel(const float* __restrict__ xm, const float* __restrict__ cw,
                        const float* __restrict__ cb, float* __restrict__ u) {
    const int idx = blockIdx.x * 256 + threadIdx.x;  // one per 4 channels
    const int m = idx >> 8;
    const int q = (idx & 255) << 2;
    const int t = m & (L_ - 1);
    float4 acc = *(const float4*)&cb[q];
    #pragma unroll
    for (int k = 0; k < 4; ++k) {
        const int tt = t - 3 + k;
        if (tt >= 0) {
            const float4 xv = *(const float4*)&xm[(size_t)(m - 3 + k) * DI_ + q];
            const float4 wv = *(const float4*)&cw[k * DI_ + q];
            acc.x += xv.x * wv.x; acc.y += xv.y * wv.y;
            acc.z += xv.z * wv.z; acc.w += xv.w * wv.w;
        }
    }
    acc.x *= sigmoid_f(acc.x); acc.y *= sigmoid_f(acc.y);
    acc.z *= sigmoid_f(acc.z); acc.w *= sigmoid_f(acc.w);
    *(float4*)&u[(size_t)m * DI_ + q] = acc;
}

// ---------------- chunked selective scan ----------------
// pass 1: local scan per chunk (h0=0), emit h_end[16] and S=sum(delta)
__global__ __launch_bounds__(64)
void scan_p1(const float* __restrict__ dptr, const float* __restrict__ uptr,
             const float* __restrict__ dbc, const float* __restrict__ A_log,
             float* __restrict__ h_end, float* __restrict__ S_out) {
    const int lane = threadIdx.x;
    int blk = blockIdx.x;                 // CB*16*NC_ blocks
    const int c = blk & (NC_ - 1);
    blk >>= 4;
    const int dg = blk & 15;
    const int b = blk >> 4;
    const int d = (dg << 6) + lane;
    float A[16], h[16];
    #pragma unroll
    for (int n = 0; n < 16; ++n) {
        A[n] = -expf(A_log[(size_t)d * DS_ + n]);
        h[n] = 0.f;
    }
    float S = 0.f;
    const size_t mbase = (size_t)b * L_ + (size_t)c * TC_;
    for (int t = 0; t < TC_; ++t) {
        const size_t m = mbase + t;
        const float de = dptr[m * DI_ + d];
        const float uu = uptr[m * DI_ + d];
        const float4* bp = (const float4*)&dbc[m * 64 + 32];
        const float4 b0 = bp[0], b1 = bp[1], b2 = bp[2], b3 = bp[3];
        S += de;
        const float du = de * uu;
        #define P1S(n_, bb_) h[n_] = __expf(de * A[n_]) * h[n_] + du * (bb_);
        P1S(0, b0.x) P1S(1, b0.y) P1S(2, b0.z) P1S(3, b0.w)
        P1S(4, b1.x) P1S(5, b1.y) P1S(6, b1.z) P1S(7, b1.w)
        P1S(8, b2.x) P1S(9, b2.y) P1S(10, b2.z) P1S(11, b2.w)
        P1S(12, b3.x) P1S(13, b3.y) P1S(14, b3.z) P1S(15, b3.w)
        #undef P1S
    }
    const size_t o = (((size_t)b * DI_ + d) * NC_ + c) * 16;
    float4* hp = (float4*)&h_end[o];
    hp[0] = make_float4(h[0], h[1], h[2], h[3]);
    hp[1] = make_float4(h[4], h[5], h[6], h[7]);
    hp[2] = make_float4(h[8], h[9], h[10], h[11]);
    hp[3] = make_float4(h[12], h[13], h[14], h[15]);
    S_out[((size_t)b * DI_ + d) * NC_ + c] = S;
}

// combine: sequential over chunks, h_init[c+1] = exp(A*S[c])*h_init[c] + h_end[c]
__global__ __launch_bounds__(64)
void scan_combine(const float* __restrict__ h_end, const float* __restrict__ S,
                  const float* __restrict__ A_log, float* __restrict__ h_init) {
    const int idx = blockIdx.x * 64 + threadIdx.x;  // CB*1024 threads
    const int b = idx >> 10;
    const int d = idx & 1023;
    float A[16], h[16];
    #pragma unroll
    for (int n = 0; n < 16; ++n) {
        A[n] = -expf(A_log[(size_t)d * DS_ + n]);
        h[n] = 0.f;
    }
    for (int c = 0; c < NC_; ++c) {
        const size_t o = (((size_t)b * DI_ + d) * NC_ + c) * 16;
        float4* hip = (float4*)&h_init[o];
        hip[0] = make_float4(h[0], h[1], h[2], h[3]);
        hip[1] = make_float4(h[4], h[5], h[6], h[7]);
        hip[2] = make_float4(h[8], h[9], h[10], h[11]);
        hip[3] = make_float4(h[12], h[13], h[14], h[15]);
        const float4* hep = (const float4*)&h_end[o];
        const float4 e0 = hep[0], e1 = hep[1], e2 = hep[2], e3 = hep[3];
        const float s = S[((size_t)b * DI_ + d) * NC_ + c];
        #define CMB(n_, ee_) h[n_] = __expf(A[n_] * s) * h[n_] + (ee_);
        CMB(0, e0.x) CMB(1, e0.y) CMB(2, e0.z) CMB(3, e0.w)
        CMB(4, e1.x) CMB(5, e1.y) CMB(6, e1.z) CMB(7, e1.w)
        CMB(8, e2.x) CMB(9, e2.y) CMB(10, e2.z) CMB(11, e2.w)
        CMB(12, e3.x) CMB(13, e3.y) CMB(14, e3.z) CMB(15, e3.w)
        #undef CMB
    }
}

// pass 2: full scan per chunk seeded with h_init; fused +u*D and *silu(z); y in place over z
__global__ __launch_bounds__(64)
void scan_p2(const float* __restrict__ dptr, const float* __restrict__ uptr,
             const float* __restrict__ dbc, float* __restrict__ zyptr,
             const float* __restrict__ A_log, const float* __restrict__ Dp,
             const float* __restrict__ h_init) {
    const int lane = threadIdx.x;
    int blk = blockIdx.x;
    const int c = blk & (NC_ - 1);
    blk >>= 4;
    const int dg = blk & 15;
    const int b = blk >> 4;
    const int d = (dg << 6) + lane;
    float A[16], h[16];
    #pragma unroll
    for (int n = 0; n < 16; ++n)
        A[n] = -expf(A_log[(size_t)d * DS_ + n]);
    {
        const size_t o = (((size_t)b * DI_ + d) * NC_ + c) * 16;
        const float4* hip = (const float4*)&h_init[o];
        const float4 i0 = hip[0], i1 = hip[1], i2 = hip[2], i3 = hip[3];
        h[0] = i0.x; h[1] = i0.y; h[2] = i0.z; h[3] = i0.w;
        h[4] = i1.x; h[5] = i1.y; h[6] = i1.z; h[7] = i1.w;
        h[8] = i2.x; h[9] = i2.y; h[10] = i2.z; h[11] = i2.w;
        h[12] = i3.x; h[13] = i3.y; h[14] = i3.z; h[15] = i3.w;
    }
    const float Dv = Dp[d];
    const size_t mbase = (size_t)b * L_ + (size_t)c * TC_;
    for (int t = 0; t < TC_; ++t) {
        const size_t m = mbase + t;
        const float de = dptr[m * DI_ + d];
        const float uu = uptr[m * DI_ + d];
        const float zv = zyptr[m * DI_ + d];
        const float4* bcp = (const float4*)&dbc[m * 64 + 32];
        const float4 b0 = bcp[0], b1 = bcp[1], b2 = bcp[2], b3 = bcp[3];
        const float4 c0 = bcp[4], c1 = bcp[5], c2 = bcp[6], c3 = bcp[7];
        const float du = de * uu;
        float y = 0.f;
        #define P2S(n_, bb_, cc_) { \
            h[n_] = __expf(de * A[n_]) * h[n_] + du * (bb_); \
            y += h[n_] * (cc_); }
        P2S(0, b0.x, c0.x) P2S(1, b0.y, c0.y) P2S(2, b0.z, c0.z) P2S(3, b0.w, c0.w)
        P2S(4, b1.x, c1.x) P2S(5, b1.y, c1.y) P2S(6, b1.z, c1.z) P2S(7, b1.w, c1.w)
        P2S(8, b2.x, c2.x) P2S(9, b2.y, c2.y) P2S(10, b2.z, c2.z) P2S(11, b2.w, c2.w)
        P2S(12, b3.x, c3.x) P2S(13, b3.y, c3.y) P2S(14, b3.z, c3.z) P2S(15, b3.w, c3.w)
        #undef P2S
        zyptr[m * DI_ + d] = (y + uu * Dv) * (zv * sigmoid_f(zv));
    }
}

// ---------------- 8. final projection (N=1) ----------------
__global__ __launch_bounds__(64)
void finalproj_kernel(const float* __restrict__ xo, const float* __restrict__ pw,
                      const float* __restrict__ pb, float* __restrict__ out) {
    const int m = blockIdx.x;
    const int lane = threadIdx.x;
    const float4 a0 = *(const float4*)&xo[(size_t)m * DM_ + lane * 4];
    const float4 a1 = *(const float4*)&xo[(size_t)m * DM_ + 256 + lane * 4];
    const float4 w0 = *(const float4*)&pw[lane * 4];
    const float4 w1 = *(const float4*)&pw[256 + lane * 4];
    float s = a0.x * w0.x + a0.y * w0.y + a0.z * w0.z + a0.w * w0.w +
              a1.x * w1.x + a1.y * w1.y + a1.z * w1.z + a1.w * w1.w;
    #pragma unroll
    for (int off = 32; off; off >>= 1) s += __shfl_down(s, off);
    if (lane == 0) out[m] = s + pb[0];
}

extern "C" void kernel_launch(void* const* d_in, const int* in_sizes, int n_in,
                              void* d_out, int out_size, void* d_ws, size_t ws_size,
                              hipStream_t stream) {
    const float* x_enc     = (const float*)d_in[0];
    const float* x_mark    = (const float*)d_in[1];
    const float* pos_emb   = (const float*)d_in[4];
    const float* conv_tok_w= (const float*)d_in[5];
    const float* temp_w    = (const float*)d_in[6];
    const float* in_proj_w = (const float*)d_in[7];
    const float* conv1d_w  = (const float*)d_in[8];
    const float* conv1d_b  = (const float*)d_in[9];
    const float* x_proj_w  = (const float*)d_in[10];
    const float* dt_proj_w = (const float*)d_in[11];
    const float* dt_proj_b = (const float*)d_in[12];
    const float* A_log     = (const float*)d_in[13];
    const float* D_param   = (const float*)d_in[14];
    const float* out_proj_w= (const float*)d_in[15];
    const float* proj_w    = (const float*)d_in[16];
    const float* proj_b    = (const float*)d_in[17];

    // per-batch region sizes (floats)
    const size_t R4b = (size_t)L_ * DM_;   // x / (dbc + scan scratch)
    const size_t R1b = (size_t)L_ * DI_;   // xm / delta
    const size_t perBatchFloats = R4b + 3 * R1b;  // 28MB

    int CB = 8;
    while (CB > 1 && (size_t)CB * perBatchFloats * sizeof(float) > ws_size) CB >>= 1;

    for (int c0 = 0; c0 < B_; c0 += CB) {
        const size_t Mc = (size_t)CB * L_;
        float* R4 = (float*)d_ws;              // x, later dbc + scan scratch
        float* R1 = R4 + CB * R4b;             // xm, later delta
        float* R2 = R1 + CB * R1b;             // z, y (in place)
        float* R3 = R2 + CB * R1b;             // u, later x_out
        // scan scratch inside R4 after dbc (dbc = Mc*64 floats):
        float* h_end  = R4 + Mc * 64;                       // CB*1024*NC_*16
        float* h_init = h_end + (size_t)CB * DI_ * NC_ * 16;
        float* S_buf  = h_init + (size_t)CB * DI_ * NC_ * 16;  // CB*1024*NC_

        const float* xe  = x_enc  + (size_t)c0 * L_ * ENC_IN_;
        const float* xme = x_mark + (size_t)c0 * L_ * NM_;
        float* outc = (float*)d_out + (size_t)c0 * L_;

        // 1. embedding -> x (R4)
        embed_kernel<<<dim3(CB * 128), 256, 0, stream>>>(xe, xme, pos_emb,
                                                         conv_tok_w, temp_w, R4);
        // 2a. in_proj (xm half)
        gemm_nt<0><<<dim3(DI_ / 64, Mc / 64), 256, 0, stream>>>(
            R4, DM_, in_proj_w, DM_, R1, DI_, nullptr, DM_);
        // 2b. in_proj (z half)
        gemm_nt<0><<<dim3(DI_ / 64, Mc / 64), 256, 0, stream>>>(
            R4, DM_, in_proj_w + (size_t)DI_ * DM_, DM_, R2, DI_, nullptr, DM_);
        // 3. depthwise causal conv + silu -> u (R3)
        dwconv_silu_kernel<<<dim3(Mc), 256, 0, stream>>>(R1, conv1d_w, conv1d_b, R3);
        // 4. x_proj -> dbc (R4, x dead)
        gemm_nt<0><<<dim3(1, Mc / 64), 256, 0, stream>>>(
            R3, DI_, x_proj_w, DI_, R4, 64, nullptr, DI_);
        // 5. dt_proj + softplus -> delta (R1, xm dead)
        gemm_nt<1><<<dim3(DI_ / 64, Mc / 64), 256, 0, stream>>>(
            R4, 64, dt_proj_w, 32, R1, DI_, dt_proj_b, 32);
        // 6. chunked selective scan + gating (y over z in R2)
        scan_p1<<<dim3(CB * 16 * NC_), 64, 0, stream>>>(R1, R3, R4, A_log,
                                                        h_end, S_buf);
        scan_combine<<<dim3(CB * 16), 64, 0, stream>>>(h_end, S_buf, A_log, h_init);
        scan_p2<<<dim3(CB * 16 * NC_), 64, 0, stream>>>(R1, R3, R4, R2,
                                                        A_log, D_param, h_init);
        // 7. out_proj: y [Mc,1024] -> x_out (R3, u dead)
        gemm_nt<0><<<dim3(DM_ / 64, Mc / 64), 256, 0, stream>>>(
            R2, DI_, out_proj_w, DI_, R3, DM_, nullptr, DI_);
        // 8. final projection -> out [Mc,1]
        finalproj_kernel<<<dim3(Mc), 64, 0, stream>>>(R3, proj_w, proj_b, outc);
    }
}

// Round 4
// 799.683 us; speedup vs baseline: 2.3476x; 1.4605x over previous
//
#include <hip/hip_runtime.h>
#include <hip/hip_bf16.h>
#include <math.h>

#define B_ 8
#define L_ 2048
#define ENC_IN_ 32
#define DM_ 512
#define DI_ 1024
#define DS_ 16
#define NM_ 4
#define NC_ 16    // chunks per sequence
#define TC_ 128   // chunk length (NC_*TC_ == L_)

typedef __attribute__((ext_vector_type(8))) short short8;
typedef __attribute__((ext_vector_type(4))) float f32x4;

__device__ __forceinline__ float sigmoid_f(float x) {
    return 1.f / (1.f + __expf(-x));
}
__device__ __forceinline__ float softplus_f(float v) {
    return fmaxf(v, 0.f) + log1pf(__expf(-fabsf(v)));
}
__device__ __forceinline__ unsigned short f2b(float f) {  // fp32 -> bf16 RNE
    union { float f; unsigned int u; } v; v.f = f;
    unsigned int r = v.u + 0x7FFFu + ((v.u >> 16) & 1u);
    return (unsigned short)(r >> 16);
}
__device__ __forceinline__ void gload16(const void* g, void* l) {
    __builtin_amdgcn_global_load_lds(
        (const __attribute__((address_space(1))) unsigned int*)g,
        (__attribute__((address_space(3))) unsigned int*)l, 16, 0, 0);
}

// ---------------- fp32 -> bf16 bulk convert (8 elems/thread) ----------------
__global__ __launch_bounds__(256)
void cvt_f2b_kernel(const float* __restrict__ in, unsigned short* __restrict__ out, int n) {
    const int i = (blockIdx.x * 256 + threadIdx.x) * 8;
    if (i >= n) return;
    const float4 a = *(const float4*)&in[i];
    const float4 b = *(const float4*)&in[i + 4];
    short8 o;
    o[0] = (short)f2b(a.x); o[1] = (short)f2b(a.y);
    o[2] = (short)f2b(a.z); o[3] = (short)f2b(a.w);
    o[4] = (short)f2b(b.x); o[5] = (short)f2b(b.y);
    o[6] = (short)f2b(b.z); o[7] = (short)f2b(b.w);
    *(short8*)&out[i] = o;
}

// ---------------- 1. DataEmbedding (writes x as bf16) ----------------
__global__ __launch_bounds__(256)
void embed_kernel(const float* __restrict__ x_enc, const float* __restrict__ x_mark,
                  const float* __restrict__ pos_emb, const float* __restrict__ cw,
                  const float* __restrict__ tw, unsigned short* __restrict__ x) {
    __shared__ float sx[18 * 32];
    __shared__ float sm[16 * 4];
    const int blk = blockIdx.x;
    const int b = blk >> 7, lc = blk & 127;
    const int l0 = lc << 4;
    const int tid = threadIdx.x;
    for (int i = tid; i < 18 * 32; i += 256) {
        int row = i >> 5, c = i & 31;
        int lt = (l0 + row - 1 + L_) & (L_ - 1);  // circular
        sx[i] = x_enc[((size_t)b * L_ + lt) * ENC_IN_ + c];
    }
    for (int i = tid; i < 64; i += 256) {
        int row = i >> 2;
        sm[i] = x_mark[((size_t)b * L_ + l0 + row) * NM_ + (i & 3)];
    }
    __syncthreads();
    #pragma unroll
    for (int half = 0; half < 2; ++half) {
        const int d = tid + (half << 8);
        float acc[16];
        #pragma unroll
        for (int l = 0; l < 16; ++l) acc[l] = 0.f;
        for (int i = 0; i < 96; ++i) {
            const int k = i >> 5, c = i & 31;
            const float w = cw[(size_t)i * DM_ + d];
            #pragma unroll
            for (int l = 0; l < 16; ++l)
                acc[l] += sx[(l + k) * 32 + c] * w;
        }
        const float4 tww = *(const float4*)&tw[d * 4];
        #pragma unroll
        for (int l = 0; l < 16; ++l) {
            float s = acc[l] + pos_emb[(size_t)(l0 + l) * DM_ + d];
            s += sm[l * 4 + 0] * tww.x + sm[l * 4 + 1] * tww.y +
                 sm[l * 4 + 2] * tww.z + sm[l * 4 + 3] * tww.w;
            x[((size_t)b * L_ + l0 + l) * DM_ + d] = f2b(s);
        }
    }
}

// ---------------- bf16 MFMA NT GEMM: C[m,n] = sum_k A[m,k]*B[n,k] ----------------
// 128x128 tile, BK=32, 256 threads (4 waves as 2x2 of 64x64), fp32 out
__global__ __launch_bounds__(256)
void gemm_nt_bf16(const unsigned short* __restrict__ A, int lda,
                  const unsigned short* __restrict__ Bw, int ldb,
                  float* __restrict__ C, int ldc, int K) {
    __shared__ unsigned short aT[128 * 32];
    __shared__ unsigned short bT[128 * 32];
    const int tid = threadIdx.x;
    const int lane = tid & 63;
    const int wave = tid >> 6;
    const int wr = wave >> 1, wc = wave & 1;
    const int nx = gridDim.x;
    // bijective XCD swizzle (total % 8 == 0 for all our grids)
    const int total = nx * gridDim.y;
    int lin = blockIdx.y * nx + blockIdx.x;
    lin = (lin & 7) * (total >> 3) + (lin >> 3);
    const int m0 = (lin / nx) << 7;
    const int n0 = (lin % nx) << 7;

    f32x4 acc[4][4];
    const f32x4 zero = {0.f, 0.f, 0.f, 0.f};
    #pragma unroll
    for (int i = 0; i < 4; ++i)
        #pragma unroll
        for (int j = 0; j < 4; ++j) acc[i][j] = zero;

    const int r0 = tid >> 2;          // row 0..63 within half-tile
    const int kc8 = (tid & 3) << 3;   // k chunk (elements)
    const int lrow = lane & 15;
    const int lk = (lane >> 4) << 3;

    for (int k0 = 0; k0 < K; k0 += 32) {
        __syncthreads();
        #pragma unroll
        for (int h = 0; h < 2; ++h) {
            const int row = (h << 6) + r0;
            const size_t lo = ((size_t)(h * 256 + tid)) * 8;
            gload16(A + (size_t)(m0 + row) * lda + k0 + kc8, &aT[lo]);
            gload16(Bw + (size_t)(n0 + row) * ldb + k0 + kc8, &bT[lo]);
        }
        __syncthreads();
        short8 af[4], bf[4];
        #pragma unroll
        for (int i = 0; i < 4; ++i)
            af[i] = *(const short8*)&aT[(((wr << 6) + (i << 4) + lrow) << 5) + lk];
        #pragma unroll
        for (int j = 0; j < 4; ++j)
            bf[j] = *(const short8*)&bT[(((wc << 6) + (j << 4) + lrow) << 5) + lk];
        #pragma unroll
        for (int i = 0; i < 4; ++i)
            #pragma unroll
            for (int j = 0; j < 4; ++j)
                acc[i][j] = __builtin_amdgcn_mfma_f32_16x16x32_bf16(af[i], bf[j], acc[i][j], 0, 0, 0);
    }
    const int rgrp = (lane >> 4) << 2;
    #pragma unroll
    for (int i = 0; i < 4; ++i)
        #pragma unroll
        for (int j = 0; j < 4; ++j) {
            const size_t rbase = (size_t)(m0 + (wr << 6) + (i << 4) + rgrp) * ldc;
            const int col = n0 + (wc << 6) + (j << 4) + lrow;
            #pragma unroll
            for (int r = 0; r < 4; ++r)
                C[rbase + (size_t)r * ldc + col] = acc[i][j][r];
        }
}

// ---------------- fp32 NT GEMM (kept for x_proj / dt_proj) ----------------
template <int EPI>
__global__ __launch_bounds__(256)
void gemm_nt(const float* __restrict__ A, int lda,
             const float* __restrict__ Bw, int ldb,
             float* __restrict__ C, int ldc,
             const float* __restrict__ bias, int K) {
    __shared__ float as[16][68];
    __shared__ float bs[16][68];
    const int tid = threadIdx.x;
    const int tx = tid & 15, ty = tid >> 4;
    const int m0 = blockIdx.y << 6, n0 = blockIdx.x << 6;
    const int lrow = tid >> 2;
    const int lk4 = (tid & 3) << 2;
    float acc[4][4];
    #pragma unroll
    for (int i = 0; i < 4; ++i)
        #pragma unroll
        for (int j = 0; j < 4; ++j) acc[i][j] = 0.f;
    const float* Ap = A + (size_t)(m0 + lrow) * lda + lk4;
    const float* Bp = Bw + (size_t)(n0 + lrow) * ldb + lk4;
    for (int k0 = 0; k0 < K; k0 += 16) {
        const float4 av = *(const float4*)(Ap + k0);
        const float4 bv = *(const float4*)(Bp + k0);
        __syncthreads();
        as[lk4 + 0][lrow] = av.x; as[lk4 + 1][lrow] = av.y;
        as[lk4 + 2][lrow] = av.z; as[lk4 + 3][lrow] = av.w;
        bs[lk4 + 0][lrow] = bv.x; bs[lk4 + 1][lrow] = bv.y;
        bs[lk4 + 2][lrow] = bv.z; bs[lk4 + 3][lrow] = bv.w;
        __syncthreads();
        #pragma unroll
        for (int kk = 0; kk < 16; ++kk) {
            const float4 a4 = *(const float4*)&as[kk][ty << 2];
            const float4 b4 = *(const float4*)&bs[kk][tx << 2];
            acc[0][0] += a4.x * b4.x; acc[0][1] += a4.x * b4.y;
            acc[0][2] += a4.x * b4.z; acc[0][3] += a4.x * b4.w;
            acc[1][0] += a4.y * b4.x; acc[1][1] += a4.y * b4.y;
            acc[1][2] += a4.y * b4.z; acc[1][3] += a4.y * b4.w;
            acc[2][0] += a4.z * b4.x; acc[2][1] += a4.z * b4.y;
            acc[2][2] += a4.z * b4.z; acc[2][3] += a4.z * b4.w;
            acc[3][0] += a4.w * b4.x; acc[3][1] += a4.w * b4.y;
            acc[3][2] += a4.w * b4.z; acc[3][3] += a4.w * b4.w;
        }
    }
    #pragma unroll
    for (int i = 0; i < 4; ++i) {
        const int row = m0 + (ty << 2) + i;
        const int col = n0 + (tx << 2);
        float4 o;
        o.x = acc[i][0]; o.y = acc[i][1]; o.z = acc[i][2]; o.w = acc[i][3];
        if (EPI == 1) {
            o.x = softplus_f(o.x + bias[col + 0]);
            o.y = softplus_f(o.y + bias[col + 1]);
            o.z = softplus_f(o.z + bias[col + 2]);
            o.w = softplus_f(o.w + bias[col + 3]);
        }
        *(float4*)&C[(size_t)row * ldc + col] = o;
    }
}

// ---------------- 3. causal depthwise conv1d (k=4) + bias + silu ----------------
__global__ __launch_bounds__(256)
void dwconv_silu_kernel(const float* __restrict__ xm, const float* __restrict__ cw,
                        const float* __restrict__ cb, float* __restrict__ u) {
    const int idx = blockIdx.x * 256 + threadIdx.x;
    const int m = idx >> 8;
    const int q = (idx & 255) << 2;
    const int t = m & (L_ - 1);
    float4 acc = *(const float4*)&cb[q];
    #pragma unroll
    for (int k = 0; k < 4; ++k) {
        const int tt = t - 3 + k;
        if (tt >= 0) {
            const float4 xv = *(const float4*)&xm[(size_t)(m - 3 + k) * DI_ + q];
            const float4 wv = *(const float4*)&cw[k * DI_ + q];
            acc.x += xv.x * wv.x; acc.y += xv.y * wv.y;
            acc.z += xv.z * wv.z; acc.w += xv.w * wv.w;
        }
    }
    acc.x *= sigmoid_f(acc.x); acc.y *= sigmoid_f(acc.y);
    acc.z *= sigmoid_f(acc.z); acc.w *= sigmoid_f(acc.w);
    *(float4*)&u[(size_t)m * DI_ + q] = acc;
}

// ---------------- chunked selective scan ----------------
__global__ __launch_bounds__(64)
void scan_p1(const float* __restrict__ dptr, const float* __restrict__ uptr,
             const float* __restrict__ dbc, const float* __restrict__ A_log,
             float* __restrict__ h_end, float* __restrict__ S_out) {
    const int lane = threadIdx.x;
    int blk = blockIdx.x;
    const int c = blk & (NC_ - 1);
    blk >>= 4;
    const int dg = blk & 15;
    const int b = blk >> 4;
    const int d = (dg << 6) + lane;
    float A[16], h[16];
    #pragma unroll
    for (int n = 0; n < 16; ++n) {
        A[n] = -expf(A_log[(size_t)d * DS_ + n]);
        h[n] = 0.f;
    }
    float S = 0.f;
    const size_t mbase = (size_t)b * L_ + (size_t)c * TC_;
    for (int t = 0; t < TC_; ++t) {
        const size_t m = mbase + t;
        const float de = dptr[m * DI_ + d];
        const float uu = uptr[m * DI_ + d];
        const float4* bp = (const float4*)&dbc[m * 64 + 32];
        const float4 b0 = bp[0], b1 = bp[1], b2 = bp[2], b3 = bp[3];
        S += de;
        const float du = de * uu;
        #define P1S(n_, bb_) h[n_] = __expf(de * A[n_]) * h[n_] + du * (bb_);
        P1S(0, b0.x) P1S(1, b0.y) P1S(2, b0.z) P1S(3, b0.w)
        P1S(4, b1.x) P1S(5, b1.y) P1S(6, b1.z) P1S(7, b1.w)
        P1S(8, b2.x) P1S(9, b2.y) P1S(10, b2.z) P1S(11, b2.w)
        P1S(12, b3.x) P1S(13, b3.y) P1S(14, b3.z) P1S(15, b3.w)
        #undef P1S
    }
    const size_t o = (((size_t)b * DI_ + d) * NC_ + c) * 16;
    float4* hp = (float4*)&h_end[o];
    hp[0] = make_float4(h[0], h[1], h[2], h[3]);
    hp[1] = make_float4(h[4], h[5], h[6], h[7]);
    hp[2] = make_float4(h[8], h[9], h[10], h[11]);
    hp[3] = make_float4(h[12], h[13], h[14], h[15]);
    S_out[((size_t)b * DI_ + d) * NC_ + c] = S;
}

__global__ __launch_bounds__(64)
void scan_combine(const float* __restrict__ h_end, const float* __restrict__ S,
                  const float* __restrict__ A_log, float* __restrict__ h_init) {
    const int idx = blockIdx.x * 64 + threadIdx.x;
    const int b = idx >> 10;
    const int d = idx & 1023;
    float A[16], h[16];
    #pragma unroll
    for (int n = 0; n < 16; ++n) {
        A[n] = -expf(A_log[(size_t)d * DS_ + n]);
        h[n] = 0.f;
    }
    for (int c = 0; c < NC_; ++c) {
        const size_t o = (((size_t)b * DI_ + d) * NC_ + c) * 16;
        float4* hip = (float4*)&h_init[o];
        hip[0] = make_float4(h[0], h[1], h[2], h[3]);
        hip[1] = make_float4(h[4], h[5], h[6], h[7]);
        hip[2] = make_float4(h[8], h[9], h[10], h[11]);
        hip[3] = make_float4(h[12], h[13], h[14], h[15]);
        const float4* hep = (const float4*)&h_end[o];
        const float4 e0 = hep[0], e1 = hep[1], e2 = hep[2], e3 = hep[3];
        const float s = S[((size_t)b * DI_ + d) * NC_ + c];
        #define CMB(n_, ee_) h[n_] = __expf(A[n_] * s) * h[n_] + (ee_);
        CMB(0, e0.x) CMB(1, e0.y) CMB(2, e0.z) CMB(3, e0.w)
        CMB(4, e1.x) CMB(5, e1.y) CMB(6, e1.z) CMB(7, e1.w)
        CMB(8, e2.x) CMB(9, e2.y) CMB(10, e2.z) CMB(11, e2.w)
        CMB(12, e3.x) CMB(13, e3.y) CMB(14, e3.z) CMB(15, e3.w)
        #undef CMB
    }
}

// pass 2: seeded scan; fused +u*D and *silu(z); writes y as bf16
__global__ __launch_bounds__(64)
void scan_p2(const float* __restrict__ dptr, const float* __restrict__ uptr,
             const float* __restrict__ dbc, const float* __restrict__ zptr,
             unsigned short* __restrict__ yb, const float* __restrict__ A_log,
             const float* __restrict__ Dp, const float* __restrict__ h_init) {
    const int lane = threadIdx.x;
    int blk = blockIdx.x;
    const int c = blk & (NC_ - 1);
    blk >>= 4;
    const int dg = blk & 15;
    const int b = blk >> 4;
    const int d = (dg << 6) + lane;
    float A[16], h[16];
    #pragma unroll
    for (int n = 0; n < 16; ++n)
        A[n] = -expf(A_log[(size_t)d * DS_ + n]);
    {
        const size_t o = (((size_t)b * DI_ + d) * NC_ + c) * 16;
        const float4* hip = (const float4*)&h_init[o];
        const float4 i0 = hip[0], i1 = hip[1], i2 = hip[2], i3 = hip[3];
        h[0] = i0.x; h[1] = i0.y; h[2] = i0.z; h[3] = i0.w;
        h[4] = i1.x; h[5] = i1.y; h[6] = i1.z; h[7] = i1.w;
        h[8] = i2.x; h[9] = i2.y; h[10] = i2.z; h[11] = i2.w;
        h[12] = i3.x; h[13] = i3.y; h[14] = i3.z; h[15] = i3.w;
    }
    const float Dv = Dp[d];
    const size_t mbase = (size_t)b * L_ + (size_t)c * TC_;
    for (int t = 0; t < TC_; ++t) {
        const size_t m = mbase + t;
        const float de = dptr[m * DI_ + d];
        const float uu = uptr[m * DI_ + d];
        const float zv = zptr[m * DI_ + d];
        const float4* bcp = (const float4*)&dbc[m * 64 + 32];
        const float4 b0 = bcp[0], b1 = bcp[1], b2 = bcp[2], b3 = bcp[3];
        const float4 c0 = bcp[4], c1 = bcp[5], c2 = bcp[6], c3 = bcp[7];
        const float du = de * uu;
        float y = 0.f;
        #define P2S(n_, bb_, cc_) { \
            h[n_] = __expf(de * A[n_]) * h[n_] + du * (bb_); \
            y += h[n_] * (cc_); }
        P2S(0, b0.x, c0.x) P2S(1, b0.y, c0.y) P2S(2, b0.z, c0.z) P2S(3, b0.w, c0.w)
        P2S(4, b1.x, c1.x) P2S(5, b1.y, c1.y) P2S(6, b1.z, c1.z) P2S(7, b1.w, c1.w)
        P2S(8, b2.x, c2.x) P2S(9, b2.y, c2.y) P2S(10, b2.z, c2.z) P2S(11, b2.w, c2.w)
        P2S(12, b3.x, c3.x) P2S(13, b3.y, c3.y) P2S(14, b3.z, c3.z) P2S(15, b3.w, c3.w)
        #undef P2S
        yb[m * DI_ + d] = f2b((y + uu * Dv) * (zv * sigmoid_f(zv)));
    }
}

// ---------------- 8. final projection (N=1) ----------------
__global__ __launch_bounds__(64)
void finalproj_kernel(const float* __restrict__ xo, const float* __restrict__ pw,
                      const float* __restrict__ pb, float* __restrict__ out) {
    const int m = blockIdx.x;
    const int lane = threadIdx.x;
    const float4 a0 = *(const float4*)&xo[(size_t)m * DM_ + lane * 4];
    const float4 a1 = *(const float4*)&xo[(size_t)m * DM_ + 256 + lane * 4];
    const float4 w0 = *(const float4*)&pw[lane * 4];
    const float4 w1 = *(const float4*)&pw[256 + lane * 4];
    float s = a0.x * w0.x + a0.y * w0.y + a0.z * w0.z + a0.w * w0.w +
              a1.x * w1.x + a1.y * w1.y + a1.z * w1.z + a1.w * w1.w;
    #pragma unroll
    for (int off = 32; off; off >>= 1) s += __shfl_down(s, off);
    if (lane == 0) out[m] = s + pb[0];
}

extern "C" void kernel_launch(void* const* d_in, const int* in_sizes, int n_in,
                              void* d_out, int out_size, void* d_ws, size_t ws_size,
                              hipStream_t stream) {
    const float* x_enc     = (const float*)d_in[0];
    const float* x_mark    = (const float*)d_in[1];
    const float* pos_emb   = (const float*)d_in[4];
    const float* conv_tok_w= (const float*)d_in[5];
    const float* temp_w    = (const float*)d_in[6];
    const float* in_proj_w = (const float*)d_in[7];
    const float* conv1d_w  = (const float*)d_in[8];
    const float* conv1d_b  = (const float*)d_in[9];
    const float* x_proj_w  = (const float*)d_in[10];
    const float* dt_proj_w = (const float*)d_in[11];
    const float* dt_proj_b = (const float*)d_in[12];
    const float* A_log     = (const float*)d_in[13];
    const float* D_param   = (const float*)d_in[14];
    const float* out_proj_w= (const float*)d_in[15];
    const float* proj_w    = (const float*)d_in[16];
    const float* proj_b    = (const float*)d_in[17];

    // fixed weight area (bf16): in_proj_w (2048*512) + out_proj_w (512*1024)
    const size_t nInW  = (size_t)2 * DI_ * DM_;   // 1,048,576
    const size_t nOutW = (size_t)DM_ * DI_;       //   524,288
    unsigned short* wb_in  = (unsigned short*)d_ws;
    unsigned short* wb_out = wb_in + nInW;
    float* chunkBase = (float*)(wb_out + nOutW);  // (nInW+nOutW)*2B = 3MB, 16B aligned

    // per-batch region sizes (floats)
    const size_t R4b = (size_t)L_ * DM_;          // x_bf16 / (dbc + scan scratch)
    const size_t R1b = (size_t)L_ * DI_;          // xm / delta
    const size_t R5b = (size_t)L_ * DI_ / 2;      // y_bf16
    const size_t perBatchFloats = R4b + 3 * R1b + R5b;  // 8M floats = 32MB
    const size_t availFloats = (ws_size - (nInW + nOutW) * 2) / 4;

    int CB = 8;
    while (CB > 1 && (size_t)CB * perBatchFloats > availFloats) CB >>= 1;

    // weight conversion (once per launch)
    cvt_f2b_kernel<<<dim3((nInW / 8 + 255) / 256), 256, 0, stream>>>(in_proj_w, wb_in, (int)nInW);
    cvt_f2b_kernel<<<dim3((nOutW / 8 + 255) / 256), 256, 0, stream>>>(out_proj_w, wb_out, (int)nOutW);

    for (int c0 = 0; c0 < B_; c0 += CB) {
        const size_t Mc = (size_t)CB * L_;
        float* R4 = chunkBase;                 // x_bf16, later dbc + scan scratch
        float* R1 = R4 + CB * R4b;             // xm, later delta
        float* R2 = R1 + CB * R1b;             // z
        float* R3 = R2 + CB * R1b;             // u, later x_out
        float* R5 = R3 + CB * R1b;             // y_bf16
        unsigned short* xb = (unsigned short*)R4;
        unsigned short* yb = (unsigned short*)R5;
        // scan scratch inside R4 after dbc (dbc = Mc*64 floats)
        float* h_end  = R4 + Mc * 64;
        float* h_init = h_end + (size_t)CB * DI_ * NC_ * 16;
        float* S_buf  = h_init + (size_t)CB * DI_ * NC_ * 16;

        const float* xe  = x_enc  + (size_t)c0 * L_ * ENC_IN_;
        const float* xme = x_mark + (size_t)c0 * L_ * NM_;
        float* outc = (float*)d_out + (size_t)c0 * L_;

        // 1. embedding -> x_bf16 (R4)
        embed_kernel<<<dim3(CB * 128), 256, 0, stream>>>(xe, xme, pos_emb,
                                                         conv_tok_w, temp_w, xb);
        // 2a. in_proj (xm half): bf16 MFMA
        gemm_nt_bf16<<<dim3(DI_ / 128, Mc / 128), 256, 0, stream>>>(
            xb, DM_, wb_in, DM_, R1, DI_, DM_);
        // 2b. in_proj (z half)
        gemm_nt_bf16<<<dim3(DI_ / 128, Mc / 128), 256, 0, stream>>>(
            xb, DM_, wb_in + (size_t)DI_ * DM_, DM_, R2, DI_, DM_);
        // 3. depthwise causal conv + silu -> u (R3)
        dwconv_silu_kernel<<<dim3(Mc), 256, 0, stream>>>(R1, conv1d_w, conv1d_b, R3);
        // 4. x_proj -> dbc (R4, x dead)  [fp32]
        gemm_nt<0><<<dim3(1, Mc / 64), 256, 0, stream>>>(
            R3, DI_, x_proj_w, DI_, R4, 64, nullptr, DI_);
        // 5. dt_proj + softplus -> delta (R1, xm dead)  [fp32]
        gemm_nt<1><<<dim3(DI_ / 64, Mc / 64), 256, 0, stream>>>(
            R4, 64, dt_proj_w, 32, R1, DI_, dt_proj_b, 32);
        // 6. chunked selective scan + gating -> y_bf16 (R5)
        scan_p1<<<dim3(CB * 16 * NC_), 64, 0, stream>>>(R1, R3, R4, A_log,
                                                        h_end, S_buf);
        scan_combine<<<dim3(CB * 16), 64, 0, stream>>>(h_end, S_buf, A_log, h_init);
        scan_p2<<<dim3(CB * 16 * NC_), 64, 0, stream>>>(R1, R3, R4, R2, yb,
                                                        A_log, D_param, h_init);
        // 7. out_proj: y_bf16 [Mc,1024] x out_w_bf16 -> x_out (R3, u dead)
        gemm_nt_bf16<<<dim3(DM_ / 128, Mc / 128), 256, 0, stream>>>(
            yb, DI_, wb_out, DI_, R3, DM_, DI_);
        // 8. final projection -> out [Mc,1]
        finalproj_kernel<<<dim3(Mc), 64, 0, stream>>>(R3, proj_w, proj_b, outc);
    }
}